// Round 7
// baseline (560.742 us; speedup 1.0000x reference)
//
#include <hip/hip_runtime.h>

#define BATCH   128
#define NUM_IN  4096
#define LVL     8
#define HID     32768
#define KH      32
#define OUTN    256
#define KOUT    64
#define SCALEA  4.9f

// Input u8 affine quantization range [-QR, QR]
#define QR      6.0f
#define QSTEP   (2.0f * QR / 255.0f)   // dequant scale
#define INV255  (1.0f / 255.0f)

#define NODES   266240              // NUM_IN + LVL*HID

// Dual act tables (both u8 pairs), written by every producer:
//  ext128[node][bp0..63]  : full-batch 128-B records  -> L3-path gathers
//  ext16 [s][node][pos0..7]: 8 batch-slices, 16-B/node -> L2-path gathers
//   (slice s = XCD s under round-robin blockIdx%8; footprint <= 3.73 MB/XCD)
//
// Round-6 post-mortem: role-by-block-range serialized the two paths in
// dispatch order (27us L3 phase + 16us L2 tail = 41.5us observed).  Roles are
// now INTERLEAVED per 32-block chunk (24 L3-role + 8 L2-role, octet aligned so
// bid%8 == slice still holds) -> both resource pools active concurrently.
// Model: max(36f, 12.3f + 65(1-f)) at f=0.75 -> ~27us/level.
#define H3      24576               // L3-path rows per level (f = 0.75)
#define H2      (HID - H3)          // 8192 L2-path rows
#define SLICE_U (NODES * 8u)        // ushorts per ext16 slice
#define SLICE_B (NODES * 16u)       // bytes per ext16 slice

__device__ __forceinline__ unsigned short f2bf(float f) {
    unsigned u = __float_as_uint(f);
    u += 0x7FFFu + ((u >> 16) & 1u);   // round-to-nearest-even
    return (unsigned short)(u >> 16);
}
__device__ __forceinline__ float bf_lo(unsigned u) { return __uint_as_float(u << 16); }
__device__ __forceinline__ float bf_hi(unsigned u) { return __uint_as_float(u & 0xFFFF0000u); }

__device__ __forceinline__ unsigned q_in(float x) {   // input -> u8, range [-QR, QR]
    float t = (x + QR) * (255.0f / (2.0f * QR));
    t = fminf(fmaxf(t, 0.f), 255.f);
    return __float2uint_rn(t);
}

// ---------------------------------------------------------------------------
// Transpose x [B, NUM_IN] f32 -> in_bf (bf16 pairs, for level0) + input region
// of BOTH act tables.
// ---------------------------------------------------------------------------
__global__ __launch_bounds__(256) void transpose_x(const float* __restrict__ x,
                                                   unsigned* __restrict__ in_bf,
                                                   unsigned short* __restrict__ ext128,
                                                   unsigned short* __restrict__ ext16) {
    __shared__ float lds[64][129];
    const int n0 = blockIdx.x * 64;
    const int t  = threadIdx.x;
    #pragma unroll
    for (int it = 0; it < 32; ++it) {
        int i = it * 256 + t;
        int b = i >> 6;
        int n = i & 63;
        lds[n][b] = x[b * NUM_IN + n0 + n];
    }
    __syncthreads();
    #pragma unroll
    for (int it = 0; it < 16; ++it) {
        int i  = it * 256 + t;      // 64 nodes x 64 batch-pairs
        int n  = i >> 6;
        int bp = i & 63;
        float v0 = lds[n][2 * bp], v1 = lds[n][2 * bp + 1];
        in_bf[(n0 + n) * 64 + bp] = (unsigned)f2bf(v0) | ((unsigned)f2bf(v1) << 16);
        unsigned short q = (unsigned short)(q_in(v0) | (q_in(v1) << 8));
        ext128[(unsigned)(n0 + n) * 64u + (unsigned)bp] = q;
        ext16[(unsigned)(bp >> 3) * SLICE_U + (unsigned)(n0 + n) * 8u + (unsigned)(bp & 7)] = q;
    }
}

// ---------------------------------------------------------------------------
// Level 0: all sources are inputs. bf16 gathers from the 1 MB L2-resident
// in_bf table; dual-writes u8 acts.
// ---------------------------------------------------------------------------
__global__ __launch_bounds__(256) void level0(const unsigned* __restrict__ in_bf,
                                              unsigned short* __restrict__ ext128,
                                              unsigned short* __restrict__ ext16,
                                              const int* __restrict__ idx,
                                              const float* __restrict__ w) {
    const int lane = threadIdx.x & 63;
    int h = (blockIdx.x << 2) + (threadIdx.x >> 6);
    h = __builtin_amdgcn_readfirstlane(h);
    const int*   ip = idx + h * KH;
    const float* wp = w   + h * KH;
    float ax = 0.f, ay = 0.f;
    #pragma unroll
    for (int k = 0; k < KH; ++k) {
        int   j  = __builtin_amdgcn_readfirstlane(ip[k]);
        float wk = wp[k];
        unsigned v = in_bf[(unsigned)j * 64 + lane];
        ax = fmaf(wk, bf_lo(v), ax);
        ay = fmaf(wk, bf_hi(v), ay);
    }
    unsigned qx = __float2uint_rn(255.f / (1.f + __expf(-SCALEA * ax)));
    unsigned qy = __float2uint_rn(255.f / (1.f + __expf(-SCALEA * ay)));
    unsigned short q = (unsigned short)(qx | (qy << 8));
    ext128[(unsigned)(NUM_IN + h) * 64u + (unsigned)lane] = q;
    ext16[(unsigned)(lane >> 3) * SLICE_U + (unsigned)(NUM_IN + h) * 8u + (unsigned)(lane & 7)] = q;
}

// ---------------------------------------------------------------------------
// Levels 1..7, dual-path with per-chunk role interleave.
// Chunk = 32 consecutive blocks: r = bid&31.
//   r in [0,24): L3 role — wave = one h, 64 lanes full batch, 128-B NT gather
//                per (h,k) from ext128.  h = (chunk*24 + r)*4 + wid.
//   r in [24,32): L2 role — slice s = bid&7 (== r&7, chunk base 32-aligned),
//                32 h per block from the top H2 rows, 16-B L2-local gathers.
// Both roles co-resident at 3:1 throughout the level -> concurrent use of
// L3 bandwidth and per-CU/L2 request slots.
// ---------------------------------------------------------------------------
__global__ __launch_bounds__(256) void deep_dual(unsigned short* __restrict__ ext128,
                                                 unsigned short* __restrict__ ext16,
                                                 const int* __restrict__ idx,
                                                 const float* __restrict__ w,
                                                 int nbase) {  // NUM_IN + l*HID
    __shared__ unsigned long long tile[32 * 33];
    const int t    = threadIdx.x;
    const int bid  = blockIdx.x;
    const int c    = bid >> 5;          // chunk 0..255
    const int r    = bid & 31;          // role slot within chunk
    const int lane = t & 63;
    const int wid  = t >> 6;

    if (r < 24) {
        // ---------------- L3 role: full-batch 128-B records ----------------
        int h = (c * 24 + r) * 4 + wid;     // 0..H3-1
        h = __builtin_amdgcn_readfirstlane(h);
        const int*   ip = idx + h * KH;
        const float* wp = w   + h * KH;
        float ax = 0.f, ay = 0.f, bias = 0.f;
        #pragma unroll
        for (int k = 0; k < KH; ++k) {
            int   j  = __builtin_amdgcn_readfirstlane(ip[k]);
            float wk = wp[k];
            bool isin = (j < NUM_IN);
            float a = wk * (isin ? QSTEP : INV255);
            bias   += isin ? (-QR * wk) : 0.f;
            unsigned tt = __builtin_nontemporal_load(
                ext128 + (unsigned)j * 64u + (unsigned)lane);
            ax = fmaf(a, (float)(tt & 0xFFu), ax);
            ay = fmaf(a, (float)(tt >> 8),   ay);
        }
        ax += bias;
        ay += bias;
        unsigned qx = __float2uint_rn(255.f / (1.f + __expf(-SCALEA * ax)));
        unsigned qy = __float2uint_rn(255.f / (1.f + __expf(-SCALEA * ay)));
        unsigned short q = (unsigned short)(qx | (qy << 8));
        ext128[(unsigned)(nbase + h) * 64u + (unsigned)lane] = q;
        ext16[(unsigned)(lane >> 3) * SLICE_U + (unsigned)(nbase + h) * 8u + (unsigned)(lane & 7)] = q;
        return;
    }

    // ------------------ L2 role: 16-B sliced records -----------------------
    const int s  = r & 7;               // == bid % 8 == XCD under round-robin
    const int hb = H3 + c * 32;         // c in [0,256) covers H2 = 8192 rows

    #pragma unroll
    for (int it = 0; it < 4; ++it) {
        int e   = it * 256 + t;         // 1024 entries = 32 h x 32 k
        int h_l = e >> 5, k = e & 31;
        int gi  = (hb + h_l) * KH + k;
        unsigned ji = (unsigned)__builtin_nontemporal_load(idx + gi);
        float    wv = __builtin_nontemporal_load(w + gi);
        tile[h_l * 33 + k] =
            (unsigned long long)ji | ((unsigned long long)__float_as_uint(wv) << 32);
    }
    __syncthreads();

    const int pos  = lane & 7;          // batch-pair within slice
    const int g    = lane >> 3;         // group -> h
    const int h_l  = wid * 8 + g;
    const char* base = (const char*)ext16 + (unsigned)s * SLICE_B + (unsigned)pos * 2u;

    float ax = 0.f, ay = 0.f, bias = 0.f;
    #pragma unroll
    for (int k = 0; k < KH; ++k) {
        unsigned long long jw = tile[h_l * 33 + k];   // broadcast within group
        unsigned j  = (unsigned)jw;
        float    wk = __uint_as_float((unsigned)(jw >> 32));
        bool isin = j < NUM_IN;
        float a = wk * (isin ? QSTEP : INV255);
        bias   += isin ? (-QR * wk) : 0.f;
        unsigned tt = *(const unsigned short*)(base + ((unsigned)j << 4));
        ax = fmaf(a, (float)(tt & 0xFFu), ax);
        ay = fmaf(a, (float)(tt >> 8),   ay);
    }
    ax += bias;
    ay += bias;

    unsigned qx = __float2uint_rn(255.f / (1.f + __expf(-SCALEA * ax)));
    unsigned qy = __float2uint_rn(255.f / (1.f + __expf(-SCALEA * ay)));
    unsigned short q = (unsigned short)(qx | (qy << 8));
    ext16[(unsigned)s * SLICE_U + (unsigned)(nbase + hb + h_l) * 8u + (unsigned)pos] = q;
    ext128[(unsigned)(nbase + hb + h_l) * 64u + (unsigned)(s * 8 + pos)] = q;
}

// ---------------------------------------------------------------------------
// Output layer: tiny (O=256); round-0 structure on ext128.
// ---------------------------------------------------------------------------
__global__ __launch_bounds__(256) void output_layer(const unsigned short* __restrict__ ext128,
                                                    const int* __restrict__ idx,
                                                    const float* __restrict__ w,
                                                    float* __restrict__ out) {
    const int lane = threadIdx.x & 63;
    int o = (blockIdx.x << 2) + (threadIdx.x >> 6);
    o = __builtin_amdgcn_readfirstlane(o);
    const int*   ip = idx + o * KOUT;
    const float* wp = w   + o * KOUT;

    float ax = 0.f, ay = 0.f, bias = 0.f;
    #pragma unroll
    for (int k = 0; k < KOUT; ++k) {
        int   j  = __builtin_amdgcn_readfirstlane(ip[k]);
        float wk = wp[k];
        bool isin = (j < NUM_IN);
        float a = wk * (isin ? QSTEP : INV255);
        bias   += isin ? (-QR * wk) : 0.f;
        unsigned tt = ext128[(unsigned)j * 64u + (unsigned)lane];
        ax = fmaf(a, (float)(tt & 0xFFu), ax);
        ay = fmaf(a, (float)(tt >> 8),   ay);
    }
    ax += bias;
    ay += bias;
    out[(2 * lane + 0) * OUTN + o] = 1.f / (1.f + __expf(-SCALEA * ax));
    out[(2 * lane + 1) * OUTN + o] = 1.f / (1.f + __expf(-SCALEA * ay));
}

extern "C" void kernel_launch(void* const* d_in, const int* in_sizes, int n_in,
                              void* d_out, int out_size, void* d_ws, size_t ws_size,
                              hipStream_t stream) {
    // setup_inputs() order: x, w_hidden, w_out, idx_hidden, idx_out
    const float* x          = (const float*)d_in[0];
    const float* w_hidden   = (const float*)d_in[1];
    const float* w_out      = (const float*)d_in[2];
    const int*   idx_hidden = (const int*)  d_in[3];
    const int*   idx_out    = (const int*)  d_in[4];
    float* out = (float*)d_out;

    char* ws = (char*)d_ws;
    unsigned*       in_bf  = (unsigned*)      (ws + 0);                    //  1,048,576 B
    unsigned short* ext128 = (unsigned short*)(ws + 1048576);              // 34,078,720 B
    unsigned short* ext16  = (unsigned short*)(ws + 1048576 + 34078720);   // 34,078,720 B

    transpose_x<<<NUM_IN / 64, 256, 0, stream>>>(x, in_bf, ext128, ext16);

    level0<<<HID / 4, 256, 0, stream>>>(in_bf, ext128, ext16, idx_hidden, w_hidden);

    const int grid_deep = 256 * 32;   // 256 chunks x (24 L3-role + 8 L2-role)
    for (int l = 1; l < LVL; ++l) {
        deep_dual<<<grid_deep, 256, 0, stream>>>(
            ext128, ext16,
            idx_hidden + (size_t)l * HID * KH,
            w_hidden   + (size_t)l * HID * KH,
            NUM_IN + l * HID);
    }
    output_layer<<<OUTN / 4, 256, 0, stream>>>(ext128, idx_out, w_out, out);
}

// Round 8
// 310.180 us; speedup vs baseline: 1.8078x; 1.8078x over previous
//
#include <hip/hip_runtime.h>

#define BATCH   128
#define NUM_IN  4096
#define LVL     8
#define HID     32768
#define KH      32
#define OUTN    256
#define KOUT    64
#define SCALEA  4.9f

// Input u8 affine quantization range [-QR, QR]
#define QR      6.0f
#define QSTEP   (2.0f * QR / 255.0f)   // dequant scale
#define INV255  (1.0f / 255.0f)

#define NODES   266240              // NUM_IN + LVL*HID

// Per-level best-path hybrid (round-7 post-mortem: paths must NOT share an
// XCD's L2 within a level; round-5/0 calibration: L2-resident sliced path is
// transaction-bound ~7.7us/M-trans, L3 path is byte-bound ~36us/level):
//   L1 (nbase=36864):  S=2 slices of 64-B records -> 2.1M trans ~17us
//   L2/L3 (<=102400):  S=4 slices of 32-B records -> 4.2M trans ~32us
//   L4..L7:            full-batch 128-B L3-path   -> ~36us (proven baseline)
// Tables: ext128[node][64 pairs] (all consumers >= L4, output)
//         s2[2][36864][32 pairs]   (L1 reads; slice = bid&1 -> XCD%2)
//         s4[4][102400][16 pairs]  (L2/L3 read; slice = bid&3 -> XCD%4)
#define S2_NODES 36864
#define S4_NODES 102400
#define S2_SLICE_U (S2_NODES * 32u)   // ushorts per s2 slice
#define S4_SLICE_U (S4_NODES * 16u)   // ushorts per s4 slice

__device__ __forceinline__ unsigned short f2bf(float f) {
    unsigned u = __float_as_uint(f);
    u += 0x7FFFu + ((u >> 16) & 1u);   // round-to-nearest-even
    return (unsigned short)(u >> 16);
}
__device__ __forceinline__ float bf_lo(unsigned u) { return __uint_as_float(u << 16); }
__device__ __forceinline__ float bf_hi(unsigned u) { return __uint_as_float(u & 0xFFFF0000u); }

__device__ __forceinline__ unsigned q_in(float x) {   // input -> u8, range [-QR, QR]
    float t = (x + QR) * (255.0f / (2.0f * QR));
    t = fminf(fmaxf(t, 0.f), 255.f);
    return __float2uint_rn(t);
}

// ---------------------------------------------------------------------------
// Transpose x [B, NUM_IN] f32 -> in_bf (bf16 pairs, for level0) + input region
// of ext128, s2, s4.
// ---------------------------------------------------------------------------
__global__ __launch_bounds__(256) void transpose_x(const float* __restrict__ x,
                                                   unsigned* __restrict__ in_bf,
                                                   unsigned short* __restrict__ ext128,
                                                   unsigned short* __restrict__ s2,
                                                   unsigned short* __restrict__ s4) {
    __shared__ float lds[64][129];
    const int n0 = blockIdx.x * 64;
    const int t  = threadIdx.x;
    #pragma unroll
    for (int it = 0; it < 32; ++it) {
        int i = it * 256 + t;
        int b = i >> 6;
        int n = i & 63;
        lds[n][b] = x[b * NUM_IN + n0 + n];
    }
    __syncthreads();
    #pragma unroll
    for (int it = 0; it < 16; ++it) {
        int i  = it * 256 + t;      // 64 nodes x 64 batch-pairs
        int n  = i >> 6;
        int bp = i & 63;
        float v0 = lds[n][2 * bp], v1 = lds[n][2 * bp + 1];
        in_bf[(n0 + n) * 64 + bp] = (unsigned)f2bf(v0) | ((unsigned)f2bf(v1) << 16);
        unsigned short q = (unsigned short)(q_in(v0) | (q_in(v1) << 8));
        unsigned node = (unsigned)(n0 + n);
        ext128[node * 64u + (unsigned)bp] = q;
        s2[(unsigned)(bp >> 5) * S2_SLICE_U + node * 32u + (unsigned)(bp & 31)] = q;
        s4[(unsigned)(bp >> 4) * S4_SLICE_U + node * 16u + (unsigned)(bp & 15)] = q;
    }
}

// ---------------------------------------------------------------------------
// Level 0: all sources are inputs. bf16 gathers from the 1 MB L2-resident
// in_bf table; writes ext128 + s2 + s4 (nodes 4096..36863).
// ---------------------------------------------------------------------------
__global__ __launch_bounds__(256) void level0(const unsigned* __restrict__ in_bf,
                                              unsigned short* __restrict__ ext128,
                                              unsigned short* __restrict__ s2,
                                              unsigned short* __restrict__ s4,
                                              const int* __restrict__ idx,
                                              const float* __restrict__ w) {
    const int lane = threadIdx.x & 63;
    int h = (blockIdx.x << 2) + (threadIdx.x >> 6);
    h = __builtin_amdgcn_readfirstlane(h);
    const int*   ip = idx + h * KH;
    const float* wp = w   + h * KH;
    float ax = 0.f, ay = 0.f;
    #pragma unroll
    for (int k = 0; k < KH; ++k) {
        int   j  = __builtin_amdgcn_readfirstlane(ip[k]);
        float wk = wp[k];
        unsigned v = in_bf[(unsigned)j * 64 + lane];
        ax = fmaf(wk, bf_lo(v), ax);
        ay = fmaf(wk, bf_hi(v), ay);
    }
    unsigned qx = __float2uint_rn(255.f / (1.f + __expf(-SCALEA * ax)));
    unsigned qy = __float2uint_rn(255.f / (1.f + __expf(-SCALEA * ay)));
    unsigned short q = (unsigned short)(qx | (qy << 8));
    unsigned node = (unsigned)(NUM_IN + h);
    ext128[node * 64u + (unsigned)lane] = q;
    s2[(unsigned)(lane >> 5) * S2_SLICE_U + node * 32u + (unsigned)(lane & 31)] = q;
    s4[(unsigned)(lane >> 4) * S4_SLICE_U + node * 16u + (unsigned)(lane & 15)] = q;
}

// ---------------------------------------------------------------------------
// Level 1: S=2 sliced path.  slice = bid&1 (XCDs {0,2,4,6} own slice 0 under
// round-robin bid%8->XCD); per-XCD footprint 36864*64B = 2.25 MB, L2-resident.
// Block = 8 h; wave = 2 groups x 32 lanes; one 64-B line per (h,k,slice).
// Unconditional branch-free k-loop (round-3 lesson).
// ---------------------------------------------------------------------------
__global__ __launch_bounds__(256) void deep_s2(const unsigned short* __restrict__ s2,
                                               unsigned short* __restrict__ ext128,
                                               unsigned short* __restrict__ s4,
                                               const int* __restrict__ idx,
                                               const float* __restrict__ w,
                                               int nbase) {  // 36864
    __shared__ unsigned long long tile[8 * 33];
    const int t   = threadIdx.x;
    const int bid = blockIdx.x;
    const int s   = bid & 1;
    const int hb  = (bid >> 1) * 8;
    {
        int h_l = t >> 5, k = t & 31;       // 256 entries = 8 h x 32 k
        int gi  = (hb + h_l) * KH + k;
        unsigned ji = (unsigned)__builtin_nontemporal_load(idx + gi);
        float    wv = __builtin_nontemporal_load(w + gi);
        tile[h_l * 33 + k] =
            (unsigned long long)ji | ((unsigned long long)__float_as_uint(wv) << 32);
    }
    __syncthreads();

    const int lane = t & 63;
    const int wid  = t >> 6;
    const int pos  = lane & 31;             // batch-pair within 64-B record
    const int g    = lane >> 5;
    const int h_l  = wid * 2 + g;
    const unsigned short* base = s2 + (unsigned)s * S2_SLICE_U + (unsigned)pos;

    float ax = 0.f, ay = 0.f, bias = 0.f;
    #pragma unroll
    for (int k = 0; k < KH; ++k) {
        unsigned long long jw = tile[h_l * 33 + k];
        unsigned j  = (unsigned)jw;
        float    wk = __uint_as_float((unsigned)(jw >> 32));
        bool isin = j < NUM_IN;
        float a = wk * (isin ? QSTEP : INV255);
        bias   += isin ? (-QR * wk) : 0.f;
        unsigned tt = base[j * 32u];
        ax = fmaf(a, (float)(tt & 0xFFu), ax);
        ay = fmaf(a, (float)(tt >> 8),   ay);
    }
    ax += bias;
    ay += bias;

    unsigned qx = __float2uint_rn(255.f / (1.f + __expf(-SCALEA * ax)));
    unsigned qy = __float2uint_rn(255.f / (1.f + __expf(-SCALEA * ay)));
    unsigned short q = (unsigned short)(qx | (qy << 8));
    unsigned node = (unsigned)(nbase + hb + h_l);
    unsigned bp   = (unsigned)(s * 32 + pos);
    ext128[node * 64u + bp] = q;
    s4[(bp >> 4) * S4_SLICE_U + node * 16u + (bp & 15)] = q;
}

// ---------------------------------------------------------------------------
// Levels 2,3: S=4 sliced path.  slice = bid&3; per-XCD footprint <=
// 102400*32B = 3.28 MB, L2-resident.  Block = 16 h; wave = 4 groups x 16
// lanes; one 32-B request per (h,k,slice).  write_s4=0 at level 3.
// ---------------------------------------------------------------------------
__global__ __launch_bounds__(256) void deep_s4(const unsigned short* __restrict__ s4in,
                                               unsigned short* __restrict__ ext128,
                                               unsigned short* __restrict__ s4out,
                                               const int* __restrict__ idx,
                                               const float* __restrict__ w,
                                               int nbase,      // 69632 / 102400
                                               int write_s4) {
    __shared__ unsigned long long tile[16 * 33];
    const int t   = threadIdx.x;
    const int bid = blockIdx.x;
    const int s   = bid & 3;
    const int hb  = (bid >> 2) * 16;
    #pragma unroll
    for (int it = 0; it < 2; ++it) {
        int e   = it * 256 + t;             // 512 entries = 16 h x 32 k
        int h_l = e >> 5, k = e & 31;
        int gi  = (hb + h_l) * KH + k;
        unsigned ji = (unsigned)__builtin_nontemporal_load(idx + gi);
        float    wv = __builtin_nontemporal_load(w + gi);
        tile[h_l * 33 + k] =
            (unsigned long long)ji | ((unsigned long long)__float_as_uint(wv) << 32);
    }
    __syncthreads();

    const int lane = t & 63;
    const int wid  = t >> 6;
    const int pos  = lane & 15;             // batch-pair within 32-B record
    const int g    = lane >> 4;
    const int h_l  = wid * 4 + g;
    const unsigned short* base = s4in + (unsigned)s * S4_SLICE_U + (unsigned)pos;

    float ax = 0.f, ay = 0.f, bias = 0.f;
    #pragma unroll
    for (int k = 0; k < KH; ++k) {
        unsigned long long jw = tile[h_l * 33 + k];
        unsigned j  = (unsigned)jw;
        float    wk = __uint_as_float((unsigned)(jw >> 32));
        bool isin = j < NUM_IN;
        float a = wk * (isin ? QSTEP : INV255);
        bias   += isin ? (-QR * wk) : 0.f;
        unsigned tt = base[j * 16u];
        ax = fmaf(a, (float)(tt & 0xFFu), ax);
        ay = fmaf(a, (float)(tt >> 8),   ay);
    }
    ax += bias;
    ay += bias;

    unsigned qx = __float2uint_rn(255.f / (1.f + __expf(-SCALEA * ax)));
    unsigned qy = __float2uint_rn(255.f / (1.f + __expf(-SCALEA * ay)));
    unsigned short q = (unsigned short)(qx | (qy << 8));
    unsigned node = (unsigned)(nbase + hb + h_l);
    unsigned bp   = (unsigned)(s * 16 + pos);
    ext128[node * 64u + bp] = q;
    if (write_s4)                           // uniform scalar branch
        s4out[(unsigned)s * S4_SLICE_U + node * 16u + (unsigned)pos] = q;
}

// ---------------------------------------------------------------------------
// Levels 4..7: proven baseline L3-path.  Wave = one h, 64 lanes full batch,
// one 128-B gather per (h,k).  ~36us/level, L3-byte-bound.
// ---------------------------------------------------------------------------
__global__ __launch_bounds__(256) void deep128(unsigned short* __restrict__ ext128,
                                               const int* __restrict__ idx,
                                               const float* __restrict__ w,
                                               int nbase) {  // NUM_IN + l*HID
    const int lane = threadIdx.x & 63;
    int h = (blockIdx.x << 2) + (threadIdx.x >> 6);
    h = __builtin_amdgcn_readfirstlane(h);
    const int*   ip = idx + h * KH;
    const float* wp = w   + h * KH;

    float ax = 0.f, ay = 0.f, bias = 0.f;
    #pragma unroll
    for (int k = 0; k < KH; ++k) {
        int   j  = __builtin_amdgcn_readfirstlane(ip[k]);
        float wk = wp[k];
        bool isin = (j < NUM_IN);
        float a = wk * (isin ? QSTEP : INV255);
        bias   += isin ? (-QR * wk) : 0.f;
        unsigned tt = ext128[(unsigned)j * 64u + (unsigned)lane];
        ax = fmaf(a, (float)(tt & 0xFFu), ax);
        ay = fmaf(a, (float)(tt >> 8),   ay);
    }
    ax += bias;
    ay += bias;

    unsigned qx = __float2uint_rn(255.f / (1.f + __expf(-SCALEA * ax)));
    unsigned qy = __float2uint_rn(255.f / (1.f + __expf(-SCALEA * ay)));
    ext128[(unsigned)(nbase + h) * 64u + (unsigned)lane] =
        (unsigned short)(qx | (qy << 8));
}

// ---------------------------------------------------------------------------
// Output layer: tiny (O=256); baseline structure on ext128.
// ---------------------------------------------------------------------------
__global__ __launch_bounds__(256) void output_layer(const unsigned short* __restrict__ ext128,
                                                    const int* __restrict__ idx,
                                                    const float* __restrict__ w,
                                                    float* __restrict__ out) {
    const int lane = threadIdx.x & 63;
    int o = (blockIdx.x << 2) + (threadIdx.x >> 6);
    o = __builtin_amdgcn_readfirstlane(o);
    const int*   ip = idx + o * KOUT;
    const float* wp = w   + o * KOUT;

    float ax = 0.f, ay = 0.f, bias = 0.f;
    #pragma unroll
    for (int k = 0; k < KOUT; ++k) {
        int   j  = __builtin_amdgcn_readfirstlane(ip[k]);
        float wk = wp[k];
        bool isin = (j < NUM_IN);
        float a = wk * (isin ? QSTEP : INV255);
        bias   += isin ? (-QR * wk) : 0.f;
        unsigned tt = ext128[(unsigned)j * 64u + (unsigned)lane];
        ax = fmaf(a, (float)(tt & 0xFFu), ax);
        ay = fmaf(a, (float)(tt >> 8),   ay);
    }
    ax += bias;
    ay += bias;
    out[(2 * lane + 0) * OUTN + o] = 1.f / (1.f + __expf(-SCALEA * ax));
    out[(2 * lane + 1) * OUTN + o] = 1.f / (1.f + __expf(-SCALEA * ay));
}

extern "C" void kernel_launch(void* const* d_in, const int* in_sizes, int n_in,
                              void* d_out, int out_size, void* d_ws, size_t ws_size,
                              hipStream_t stream) {
    // setup_inputs() order: x, w_hidden, w_out, idx_hidden, idx_out
    const float* x          = (const float*)d_in[0];
    const float* w_hidden   = (const float*)d_in[1];
    const float* w_out      = (const float*)d_in[2];
    const int*   idx_hidden = (const int*)  d_in[3];
    const int*   idx_out    = (const int*)  d_in[4];
    float* out = (float*)d_out;

    char* ws = (char*)d_ws;
    unsigned*       in_bf  = (unsigned*)      (ws + 0);           //  1,048,576 B
    unsigned short* ext128 = (unsigned short*)(ws + 1048576);     // 34,078,720 B
    unsigned short* s2     = (unsigned short*)(ws + 35127296);    //  4,718,592 B
    unsigned short* s4     = (unsigned short*)(ws + 39845888);    // 13,107,200 B

    transpose_x<<<NUM_IN / 64, 256, 0, stream>>>(x, in_bf, ext128, s2, s4);

    level0<<<HID / 4, 256, 0, stream>>>(in_bf, ext128, s2, s4, idx_hidden, w_hidden);

    // Level 1: S=2 sliced (reads s2, writes ext128 + s4)
    deep_s2<<<(HID / 8) * 2, 256, 0, stream>>>(
        s2, ext128, s4,
        idx_hidden + (size_t)1 * HID * KH,
        w_hidden   + (size_t)1 * HID * KH,
        NUM_IN + 1 * HID);

    // Levels 2,3: S=4 sliced (read s4; level 2 also writes s4)
    for (int l = 2; l <= 3; ++l) {
        deep_s4<<<(HID / 16) * 4, 256, 0, stream>>>(
            s4, ext128, s4,
            idx_hidden + (size_t)l * HID * KH,
            w_hidden   + (size_t)l * HID * KH,
            NUM_IN + l * HID,
            (l == 2) ? 1 : 0);
    }

    // Levels 4..7: baseline L3-path
    for (int l = 4; l < LVL; ++l) {
        deep128<<<HID / 4, 256, 0, stream>>>(
            ext128,
            idx_hidden + (size_t)l * HID * KH,
            w_hidden   + (size_t)l * HID * KH,
            NUM_IN + l * HID);
    }

    output_layer<<<OUTN / 4, 256, 0, stream>>>(ext128, idx_out, w_out, out);
}